// Round 6
// baseline (2021.467 us; speedup 1.0000x reference)
//
#include <hip/hip_runtime.h>
#include <hip/hip_bf16.h>
#include <math.h>

// Problem constants
#define BB 128
#define SS 100
#define DD 512
#define HH 8
#define DHH 64
#define DFFF 2048
#define RR 199          // 2S-1
#define MM (BB*SS)      // 12800
#define NLAYERS 6
#define SCALE_ 0.125f

typedef __attribute__((ext_vector_type(8))) short bf16x8;
typedef __attribute__((ext_vector_type(4))) short bf16x4;
typedef __attribute__((ext_vector_type(4))) float floatx4;

__device__ inline unsigned short f2bf(float f) {
    union { float f; unsigned u; } c; c.f = f;
    unsigned r = c.u + 0x7FFFu + ((c.u >> 16) & 1u);   // RNE
    return (unsigned short)(r >> 16);
}
__device__ inline float bf2f(unsigned short h) {
    union { unsigned u; float f; } c; c.u = ((unsigned)h) << 16;
    return c.f;
}
__device__ inline void split8(const float* x, bf16x8& hi, bf16x8& lo) {
    #pragma unroll
    for (int i = 0; i < 8; i++) {
        unsigned short h_ = f2bf(x[i]);
        hi[i] = (short)h_;
        lo[i] = (short)f2bf(x[i] - bf2f(h_));
    }
}
// async global->LDS, 16 bytes per lane (LDS dest = uniform base + lane*16)
__device__ inline void gl2lds16(const unsigned short* g, unsigned short* l) {
    __builtin_amdgcn_global_load_lds(
        (const __attribute__((address_space(1))) void*)g,
        (__attribute__((address_space(3))) void*)l, 16, 0, 0);
}
// 8B-aligned bf16x8 load (two bf16x4 halves)
__device__ inline bf16x8 ld8_u8align(const unsigned short* p) {
    bf16x4 a = *(const bf16x4*)p;
    bf16x4 b = *(const bf16x4*)(p + 4);
    return __builtin_shufflevector(a, b, 0, 1, 2, 3, 4, 5, 6, 7);
}

// panel-major offset for bf16 matrices: [k/8][ROWS][8]
#define PANEL(buf, rows, r_, k_) ((buf) + ((size_t)((k_) >> 3) * (rows) + (r_)) * 8 + ((k_) & 7))

// ---------------------------------------------------------------------------
__global__ void embed_kernel(const int* __restrict__ ids, const float* __restrict__ emb,
                             float* __restrict__ src, unsigned short* __restrict__ srcbf) {
    int r  = blockIdx.x;
    int s  = r % SS;
    int id = ids[r];
    int d0 = threadIdx.x * 4;
    const float c = logf(10000.0f) / 512.0f;
    unsigned short pk[4];
    #pragma unroll
    for (int jj = 0; jj < 4; jj++) {
        int d  = d0 + jj;
        int j2 = d & ~1;
        float freq = expf(-(float)j2 * c);
        float ang  = (float)s * freq;
        float pe   = (d & 1) ? cosf(ang) : sinf(ang);
        float x = emb[id * DD + d] + pe;
        src[r * DD + d] = x;
        pk[jj] = f2bf(x);
    }
    *(uint2*)PANEL(srcbf, MM, r, d0) = *(uint2*)pk;
}

// ---------------------------------------------------------------------------
__global__ void kpos_kernel(const float* __restrict__ Wpos, unsigned short* __restrict__ kp) {
    int r = blockIdx.x;
    float p = (float)(SS - 1 - r);
    __shared__ float pe[DD];
    int t = threadIdx.x;
    const float c = logf(10000.0f) / 512.0f;
    {
        int j2 = t & ~1;
        float freq = expf(-(float)j2 * c);
        float ang  = p * freq;
        pe[t] = (t & 1) ? cosf(ang) : sinf(ang);
    }
    __syncthreads();
    float acc = 0.0f;
    for (int k = 0; k < DD; k++) acc += pe[k] * Wpos[k * DD + t];
    kp[r * DD + t] = f2bf(acc);
}

// ---------------------------------------------------------------------------
__global__ void wtr_kernel(const float* __restrict__ W, unsigned short* __restrict__ Wt,
                           int K, int N) {
    int idx = blockIdx.x * 256 + threadIdx.x;
    if (idx >= K * N) return;
    int k = idx / N, n = idx - k * N;
    *PANEL(Wt, N, n, k) = f2bf(W[idx]);
}

// ---------------------------------------------------------------------------
// bf16 MFMA GEMM with XCD-chunked swizzle (round-5 core).
// CMODE: 0 = fp32 flat, 1 = bf16 panel (rows=M), 2 = bf16 flat,
//        3 = fused gate: xg=sigmoid(x); out=Cf*(1-xg)+Px*xg -> Cf fp32 + Cb panel
template<int ACT, int CMODE, int BN>
__global__ __launch_bounds__(256) void mgemm(const unsigned short* __restrict__ A,
                                             const unsigned short* __restrict__ Bt,
                                             const float* __restrict__ bias,
                                             float* __restrict__ Cf,
                                             unsigned short* __restrict__ Cb,
                                             int M, int N, int K,
                                             const float* __restrict__ Px) {
    const int NF = BN / 32;
    int nm = M >> 7, nn = N / BN;
    int bid = blockIdx.x;
    int xcd = bid & 7, slot = bid >> 3;
    int c0 = (xcd * nm) >> 3, c1 = ((xcd + 1) * nm) >> 3;
    int cm = c1 - c0;
    if (slot >= cm * nn) return;
    int m0 = (c0 + (slot % cm)) * 128;
    int n0 = (slot / cm) * BN;

    __shared__ __align__(16) unsigned short As[4 * 128 * 8];
    __shared__ __align__(16) unsigned short Bs[4 * BN * 8];
    int t = threadIdx.x, lane = t & 63, wave = t >> 6;
    int quad = lane >> 4, l16 = lane & 15;
    int wm = (wave & 1) * 64, wn = (wave >> 1) * (BN / 2);

    floatx4 acc[4][4];
    #pragma unroll
    for (int i = 0; i < 4; i++)
        #pragma unroll
        for (int j = 0; j < NF; j++) acc[i][j] = (floatx4){0.f, 0.f, 0.f, 0.f};

    for (int k0 = 0; k0 < K; k0 += 32) {
        __syncthreads();
        {
            const unsigned short* gA = A + ((size_t)((k0 >> 3) + wave) * M + m0) * 8;
            unsigned short* lA = As + wave * 128 * 8;
            gl2lds16(gA + lane * 8,        lA + lane * 8);
            gl2lds16(gA + (64 + lane) * 8, lA + (64 + lane) * 8);
        }
        {
            const unsigned short* gB = Bt + ((size_t)((k0 >> 3) + wave) * N + n0) * 8;
            unsigned short* lB = Bs + wave * BN * 8;
            gl2lds16(gB + lane * 8, lB + lane * 8);
            if (BN == 128) gl2lds16(gB + (64 + lane) * 8, lB + (64 + lane) * 8);
        }
        __syncthreads();
        bf16x8 af[4], bfv[4];
        #pragma unroll
        for (int mf = 0; mf < 4; mf++)
            af[mf] = *(const bf16x8*)(As + (quad * 128 + wm + mf * 16 + l16) * 8);
        #pragma unroll
        for (int nf = 0; nf < NF; nf++)
            bfv[nf] = *(const bf16x8*)(Bs + (quad * BN + wn + nf * 16 + l16) * 8);
        #pragma unroll
        for (int mf = 0; mf < 4; mf++)
            #pragma unroll
            for (int nf = 0; nf < NF; nf++)
                acc[mf][nf] = __builtin_amdgcn_mfma_f32_16x16x32_bf16(
                                  af[mf], bfv[nf], acc[mf][nf], 0, 0, 0);
    }

    #pragma unroll
    for (int nf = 0; nf < NF; nf++) {
        int col = n0 + wn + nf * 16 + l16;
        float bv = bias ? bias[col] : 0.0f;
        #pragma unroll
        for (int mf = 0; mf < 4; mf++) {
            #pragma unroll
            for (int r = 0; r < 4; r++) {
                int row = m0 + wm + mf * 16 + quad * 4 + r;
                float x = acc[mf][nf][r] + bv;
                if (ACT == 1) x = fmaxf(x, 0.0f);
                else if (ACT == 2) x = tanhf(x);
                if (CMODE == 0)      Cf[(size_t)row * N + col] = x;
                else if (CMODE == 1) *PANEL(Cb, M, row, col) = f2bf(x);
                else if (CMODE == 2) Cb[(size_t)row * N + col] = f2bf(x);
                else {  // fused sigmoid gate + combine
                    float xg = 1.0f / (1.0f + expf(-x));
                    size_t o = (size_t)row * N + col;
                    float out = Cf[o] * (1.0f - xg) + Px[o] * xg;
                    Cf[o] = out;
                    *PANEL(Cb, M, row, col) = f2bf(out);
                }
            }
        }
    }
}
static inline int mgemm_grid(int M, int N, int BN) {
    int nm = M >> 7, nn = N / BN;
    int cmmax = 0;
    for (int x = 0; x < 8; x++) {
        int c = ((x + 1) * nm) / 8 - (x * nm) / 8;
        if (c > cmmax) cmmax = c;
    }
    return 8 * cmmax * nn;
}

// ---------------------------------------------------------------------------
// MFMA fused attention v3: 512 threads (8 waves), one stripe per wave.
// DMA staging (global_load_lds) for Kp/K with XOR chunk swizzle; swizzled V;
// 116-wide pos window; packed LDS = 81,280 B -> 2 blocks/CU (16 waves).
// LDS shorts: Kp[200*64]@0, K[104*64]@12800, V[64*128]@19456, psc[7][16*116]@27648
#define LKP 0
#define LK  12800
#define LV  19456
#define LPS 27648
#define PSW 116
__global__ __launch_bounds__(512, 4) void attn_kernel3(
        const float* __restrict__ q, const unsigned short* __restrict__ kvb,
        const unsigned short* __restrict__ kpbf, const float* __restrict__ u,
        const float* __restrict__ v, const int* __restrict__ len_,
        unsigned short* __restrict__ outp) {
    __shared__ __align__(16) unsigned short lds[40640];
    int b = blockIdx.x >> 3, h = blockIdx.x & 7;
    int t = threadIdx.x, wave = t >> 6, lane = t & 63;
    int quad = lane >> 4, l16 = lane & 15;

    // ---- DMA staging: Kp (25 insts of 8 rows), K (13 insts) ----
    {
        int r8 = lane >> 3;            // row within 8-row group
        int cc = (lane & 7) ^ r8;      // swizzled source chunk
        for (int i = wave; i < 25; i += 8) {
            int row = i * 8 + r8;
            gl2lds16(kpbf + (size_t)row * DD + h * 64 + cc * 8,
                     lds + LKP + i * 512 + lane * 8);
        }
        for (int i = wave; i < 13; i += 8) {
            int row = i * 8 + r8;
            gl2lds16(kvb + (size_t)(b * SS + row) * 1024 + h * 128 + cc * 8,
                     lds + LK + i * 512 + lane * 8);
        }
    }
    // ---- V transpose staging (swizzled chunk slots -> conflict-free) ----
    for (int idx = t; idx < 8192; idx += 512) {
        int j = idx >> 6, d = idx & 63;
        unsigned short vv = kvb[(size_t)(b * SS + j) * 1024 + h * 128 + 64 + d];
        lds[LV + d * 128 + (((j >> 3) ^ (d & 15)) << 3) + (j & 7)] = vv;
    }
    int len = len_[b];
    float ua[2][8], va[2][8];
    #pragma unroll
    for (int kf = 0; kf < 2; kf++)
        #pragma unroll
        for (int i = 0; i < 8; i++) {
            ua[kf][i] = u[h * 64 + kf * 32 + quad * 8 + i];
            va[kf][i] = v[h * 64 + kf * 32 + quad * 8 + i];
        }
    __syncthreads();
    if (wave >= 7) return;

    int s = wave;
    unsigned short* psc = lds + LPS + wave * (16 * PSW);

    // ---- Q fragments (fp32 global, hi/lo split) ----
    int iq = s * 16 + l16; if (iq > 99) iq = 99;
    const float* qrow = q + ((size_t)(b * SS + iq)) * DD + h * 64;
    bf16x8 qu_h[2], qu_l[2], qv_h[2], qv_l[2];
    #pragma unroll
    for (int kf = 0; kf < 2; kf++) {
        float4 q0 = *(const float4*)(qrow + kf * 32 + quad * 8);
        float4 q1 = *(const float4*)(qrow + kf * 32 + quad * 8 + 4);
        float qa[8] = {q0.x, q0.y, q0.z, q0.w, q1.x, q1.y, q1.z, q1.w};
        float xu[8], xv[8];
        #pragma unroll
        for (int i = 0; i < 8; i++) { xu[i] = qa[i] + ua[kf][i]; xv[i] = qa[i] + va[kf][i]; }
        split8(xu, qu_h[kf], qu_l[kf]);
        split8(xv, qv_h[kf], qv_l[kf]);
    }
    // ---- content scores: B-frag row rr, swizzled chunk ----
    floatx4 cacc[7];
    #pragma unroll
    for (int nt = 0; nt < 7; nt++) cacc[nt] = (floatx4){0.f, 0.f, 0.f, 0.f};
    #pragma unroll
    for (int nt = 0; nt < 7; nt++) {
        int rr = nt * 16 + l16;
        #pragma unroll
        for (int kf = 0; kf < 2; kf++) {
            int ch = kf * 4 + quad;
            bf16x8 kb = *(const bf16x8*)(lds + LK + rr * 64 + ((ch ^ (rr & 7)) << 3));
            cacc[nt] = __builtin_amdgcn_mfma_f32_16x16x32_bf16(qu_h[kf], kb, cacc[nt], 0, 0, 0);
            cacc[nt] = __builtin_amdgcn_mfma_f32_16x16x32_bf16(qu_l[kf], kb, cacc[nt], 0, 0, 0);
        }
    }
    // ---- pos scores, 116-wide window [w0, w0+115] ----
    int w0 = 84 - 16 * s; if (w0 < 0) w0 = 0;
    {
        floatx4 pacc[8];
        #pragma unroll
        for (int nt = 0; nt < 8; nt++) pacc[nt] = (floatx4){0.f, 0.f, 0.f, 0.f};
        #pragma unroll
        for (int nt = 0; nt < 8; nt++) {
            int rr = w0 + nt * 16 + l16;
            #pragma unroll
            for (int kf = 0; kf < 2; kf++) {
                int ch = kf * 4 + quad;
                bf16x8 pb = *(const bf16x8*)(lds + LKP + rr * 64 + ((ch ^ (rr & 7)) << 3));
                pacc[nt] = __builtin_amdgcn_mfma_f32_16x16x32_bf16(qv_h[kf], pb, pacc[nt], 0, 0, 0);
                pacc[nt] = __builtin_amdgcn_mfma_f32_16x16x32_bf16(qv_l[kf], pb, pacc[nt], 0, 0, 0);
            }
        }
        #pragma unroll
        for (int nt = 0; nt < 7; nt++)
            #pragma unroll
            for (int r = 0; r < 4; r++)
                psc[(quad * 4 + r) * PSW + nt * 16 + l16] = f2bf(pacc[nt][r]);
        if (l16 < 4)
            #pragma unroll
            for (int r = 0; r < 4; r++)
                psc[(quad * 4 + r) * PSW + 112 + l16] = f2bf(pacc[7][r]);
    }
    // ---- assemble + softmax (fp32) ----
    float sc[7][4];
    #pragma unroll
    for (int nt = 0; nt < 7; nt++)
        #pragma unroll
        for (int r = 0; r < 4; r++) {
            int irow = s * 16 + quad * 4 + r;
            int j = nt * 16 + l16;
            int ro = 99 - irow + j - w0;
            ro = ro < 0 ? 0 : (ro > PSW - 1 ? PSW - 1 : ro);
            float val = (cacc[nt][r] + bf2f(psc[(quad * 4 + r) * PSW + ro])) * SCALE_;
            sc[nt][r] = (j < len) ? val : -1e9f;
        }
    float inv[4];
    #pragma unroll
    for (int r = 0; r < 4; r++) {
        float m_ = sc[0][r];
        #pragma unroll
        for (int nt = 1; nt < 7; nt++) m_ = fmaxf(m_, sc[nt][r]);
        #pragma unroll
        for (int o = 8; o; o >>= 1) m_ = fmaxf(m_, __shfl_xor(m_, o));
        float s_ = 0.f;
        #pragma unroll
        for (int nt = 0; nt < 7; nt++) { sc[nt][r] = expf(sc[nt][r] - m_); s_ += sc[nt][r]; }
        #pragma unroll
        for (int o = 8; o; o >>= 1) s_ += __shfl_xor(s_, o);
        inv[r] = 1.0f / s_;
    }
    // ---- PV, two passes (hi then lo); k=112..127 A-frags zeroed ----
    bf16x8 zero8 = (bf16x8){0, 0, 0, 0, 0, 0, 0, 0};
    floatx4 oacc[4];
    #pragma unroll
    for (int ntd = 0; ntd < 4; ntd++) oacc[ntd] = (floatx4){0.f, 0.f, 0.f, 0.f};
    #pragma unroll
    for (int pass = 0; pass < 2; pass++) {
        #pragma unroll
        for (int r = 0; r < 4; r++) {
            int row = quad * 4 + r;
            #pragma unroll
            for (int nt = 0; nt < 7; nt++) {
                float pv = sc[nt][r] * inv[r];
                unsigned short ph = f2bf(pv);
                psc[row * PSW + nt * 16 + l16] =
                    (pass == 0) ? ph : f2bf(pv - bf2f(ph));
            }
        }
        bf16x8 pa[4];
        #pragma unroll
        for (int kf = 0; kf < 3; kf++)
            pa[kf] = ld8_u8align(psc + l16 * PSW + kf * 32 + quad * 8);
        pa[3] = (quad < 2) ? ld8_u8align(psc + l16 * PSW + 96 + quad * 8) : zero8;
        #pragma unroll
        for (int ntd = 0; ntd < 4; ntd++) {
            int d = ntd * 16 + l16;
            #pragma unroll
            for (int kf = 0; kf < 4; kf++) {
                int ch = kf * 4 + quad;
                bf16x8 bv = *(const bf16x8*)(lds + LV + d * 128 + ((ch ^ (d & 15)) << 3));
                oacc[ntd] = __builtin_amdgcn_mfma_f32_16x16x32_bf16(pa[kf], bv, oacc[ntd], 0, 0, 0);
            }
        }
    }
    #pragma unroll
    for (int ntd = 0; ntd < 4; ntd++)
        #pragma unroll
        for (int r = 0; r < 4; r++) {
            int irow = s * 16 + quad * 4 + r;
            if (irow < 100) {
                int col = h * 64 + ntd * 16 + l16;
                int row = b * SS + irow;
                *PANEL(outp, MM, row, col) = f2bf(oacc[ntd][r]);
            }
        }
}

// ---------------------------------------------------------------------------
__global__ void ln_kernel(const float* __restrict__ x, const float* __restrict__ a,
                          const float* __restrict__ g, const float* __restrict__ bb,
                          unsigned short* __restrict__ outp) {
    int r = blockIdx.x;
    int t = threadIdx.x;
    float4 xv = *(const float4*)(x + (size_t)r * DD + t * 4);
    float4 av = *(const float4*)(a + (size_t)r * DD + t * 4);
    float v0 = xv.x + av.x, v1 = xv.y + av.y, v2 = xv.z + av.z, v3 = xv.w + av.w;
    float sum = v0 + v1 + v2 + v3;
    float sq  = v0 * v0 + v1 * v1 + v2 * v2 + v3 * v3;
    #pragma unroll
    for (int o = 32; o > 0; o >>= 1) {
        sum += __shfl_down(sum, o);
        sq  += __shfl_down(sq, o);
    }
    __shared__ float ls[2], lq[2];
    if ((t & 63) == 0) { ls[t >> 6] = sum; lq[t >> 6] = sq; }
    __syncthreads();
    float S_ = ls[0] + ls[1], Q_ = lq[0] + lq[1];
    float m   = S_ / 512.0f;
    float var = Q_ / 512.0f - m * m;
    float rs  = rsqrtf(var + 1e-5f);
    float4 gv = *(const float4*)(g  + t * 4);
    float4 bv = *(const float4*)(bb + t * 4);
    unsigned short pk[4];
    pk[0] = f2bf((v0 - m) * rs * gv.x + bv.x);
    pk[1] = f2bf((v1 - m) * rs * gv.y + bv.y);
    pk[2] = f2bf((v2 - m) * rs * gv.z + bv.z);
    pk[3] = f2bf((v3 - m) * rs * gv.w + bv.w);
    *(uint2*)PANEL(outp, MM, r, t * 4) = *(uint2*)pk;
}

// ---------------------------------------------------------------------------
extern "C" void kernel_launch(void* const* d_in, const int* in_sizes, int n_in,
                              void* d_out, int out_size, void* d_ws, size_t ws_size,
                              hipStream_t stream) {
    const int*   ids     = (const int*)  d_in[0];
    const int*   src_len = (const int*)  d_in[1];
    const float* emb     = (const float*)d_in[2];
    const float* Wq      = (const float*)d_in[3];
    const float* Wkv     = (const float*)d_in[4];
    const float* Wpos    = (const float*)d_in[5];
    const float* Wout    = (const float*)d_in[6];
    const float* u       = (const float*)d_in[7];
    const float* v       = (const float*)d_in[8];
    const float* ng      = (const float*)d_in[9];
    const float* nb      = (const float*)d_in[10];
    const float* p1_w    = (const float*)d_in[11];
    const float* p1_b    = (const float*)d_in[12];
    const float* p2_w    = (const float*)d_in[13];
    const float* p2_b    = (const float*)d_in[14];
    const float* g1_w    = (const float*)d_in[15];
    const float* g1_b    = (const float*)d_in[16];
    const float* g2_w    = (const float*)d_in[17];
    const float* g2_b    = (const float*)d_in[18];

    float* src = (float*)d_out;

    float* ws     = (float*)d_ws;
    float* q      = ws;
    float* t1     = q    + (size_t)MM * DD;
    float* proj   = t1   + (size_t)MM * DD;
    float* bg     = proj + (size_t)MM * DD;   // unused (kept for layout)
    unsigned short* kpbf  = (unsigned short*)(bg + (size_t)MM * DD);
    unsigned short* srcbf = kpbf  + (size_t)RR * DD;
    unsigned short* netbf = srcbf + (size_t)MM * DD;
    unsigned short* t0p   = netbf + (size_t)MM * DD;
    unsigned short* kvb   = t0p   + (size_t)MM * DD;
    unsigned short* ffb   = kvb   + (size_t)MM * 2 * DD;
    unsigned short* hgb   = ffb   + (size_t)MM * DFFF;
    unsigned short* wq_t   = hgb   + (size_t)MM * DD;
    unsigned short* wkv_t  = wq_t   + 512 * 512;
    unsigned short* wout_t = wkv_t  + 1024 * 512;
    unsigned short* p1_t   = wout_t + 512 * 512;
    unsigned short* p2_t   = p1_t   + 2048 * 512;
    unsigned short* g1_t   = p2_t   + 512 * 2048;
    unsigned short* g2_t   = g1_t   + 512 * 512;

    embed_kernel<<<MM, 128, 0, stream>>>(ids, emb, src, srcbf);
    kpos_kernel<<<RR, DD, 0, stream>>>(Wpos, kpbf);
    wtr_kernel<<<(512*512 +255)/256, 256, 0, stream>>>(Wq,   wq_t,   512, 512);
    wtr_kernel<<<(512*1024+255)/256, 256, 0, stream>>>(Wkv,  wkv_t,  512, 1024);
    wtr_kernel<<<(512*512 +255)/256, 256, 0, stream>>>(Wout, wout_t, 512, 512);
    wtr_kernel<<<(512*2048+255)/256, 256, 0, stream>>>(p1_w, p1_t,   512, 2048);
    wtr_kernel<<<(2048*512+255)/256, 256, 0, stream>>>(p2_w, p2_t,   2048, 512);
    wtr_kernel<<<(512*512 +255)/256, 256, 0, stream>>>(g1_w, g1_t,   512, 512);
    wtr_kernel<<<(512*512 +255)/256, 256, 0, stream>>>(g2_w, g2_t,   512, 512);

    int g64   = mgemm_grid(MM, 512, 64);
    int g128k = mgemm_grid(MM, 1024, 128);
    int g128f = mgemm_grid(MM, 2048, 128);

    for (int layer = 0; layer < NLAYERS; layer++) {
        mgemm<0,0,64><<<g64, 256, 0, stream>>>(
            srcbf, wq_t, (const float*)nullptr, q, (unsigned short*)nullptr,
            MM, 512, 512, (const float*)nullptr);
        mgemm<0,2,128><<<g128k, 256, 0, stream>>>(
            srcbf, wkv_t, (const float*)nullptr, (float*)nullptr, kvb,
            MM, 1024, 512, (const float*)nullptr);
        attn_kernel3<<<BB * HH, 512, 0, stream>>>(q, kvb, kpbf, u, v, src_len, t0p);
        mgemm<0,0,64><<<g64, 256, 0, stream>>>(
            t0p, wout_t, (const float*)nullptr, t1, (unsigned short*)nullptr,
            MM, 512, 512, (const float*)nullptr);
        ln_kernel<<<MM, 128, 0, stream>>>(src, t1, ng, nb, netbf);
        mgemm<1,1,128><<<g128f, 256, 0, stream>>>(
            netbf, p1_t, p1_b, (float*)nullptr, ffb, MM, 2048, 512,
            (const float*)nullptr);
        mgemm<2,0,64><<<g64, 256, 0, stream>>>(
            ffb, p2_t, p2_b, proj, (unsigned short*)nullptr, MM, 512, 2048,
            (const float*)nullptr);
        mgemm<1,1,64><<<g64, 256, 0, stream>>>(
            netbf, g1_t, g1_b, (float*)nullptr, hgb, MM, 512, 512,
            (const float*)nullptr);
        // fused: bg=sigmoid(hg@g2+b); src = src*(1-bg)+proj*bg; srcbf updated
        mgemm<0,3,64><<<g64, 256, 0, stream>>>(
            hgb, g2_t, g2_b, src, srcbf, MM, 512, 512, proj);
    }
}

// Round 7
// 1670.706 us; speedup vs baseline: 1.2099x; 1.2099x over previous
//
#include <hip/hip_runtime.h>
#include <hip/hip_bf16.h>
#include <math.h>

// Problem constants
#define BB 128
#define SS 100
#define DD 512
#define HH 8
#define DHH 64
#define DFFF 2048
#define RR 199          // 2S-1
#define MM (BB*SS)      // 12800
#define NLAYERS 6
#define SCALE_ 0.125f

typedef __attribute__((ext_vector_type(8))) short bf16x8;
typedef __attribute__((ext_vector_type(4))) short bf16x4;
typedef __attribute__((ext_vector_type(4))) float floatx4;

__device__ inline unsigned short f2bf(float f) {
    union { float f; unsigned u; } c; c.f = f;
    unsigned r = c.u + 0x7FFFu + ((c.u >> 16) & 1u);   // RNE
    return (unsigned short)(r >> 16);
}
__device__ inline float bf2f(unsigned short h) {
    union { unsigned u; float f; } c; c.u = ((unsigned)h) << 16;
    return c.f;
}
__device__ inline void split8(const float* x, bf16x8& hi, bf16x8& lo) {
    #pragma unroll
    for (int i = 0; i < 8; i++) {
        unsigned short h_ = f2bf(x[i]);
        hi[i] = (short)h_;
        lo[i] = (short)f2bf(x[i] - bf2f(h_));
    }
}
// async global->LDS, 16 bytes per lane (LDS dest = uniform base + lane*16)
__device__ inline void gl2lds16(const unsigned short* g, unsigned short* l) {
    __builtin_amdgcn_global_load_lds(
        (const __attribute__((address_space(1))) void*)g,
        (__attribute__((address_space(3))) void*)l, 16, 0, 0);
}
// 8B-aligned bf16x8 load (two bf16x4 halves)
__device__ inline bf16x8 ld8_u8align(const unsigned short* p) {
    bf16x4 a = *(const bf16x4*)p;
    bf16x4 b = *(const bf16x4*)(p + 4);
    return __builtin_shufflevector(a, b, 0, 1, 2, 3, 4, 5, 6, 7);
}

// panel-major offset for bf16 matrices: [k/8][ROWS][8]
#define PANEL(buf, rows, r_, k_) ((buf) + ((size_t)((k_) >> 3) * (rows) + (r_)) * 8 + ((k_) & 7))

// ---------------------------------------------------------------------------
__global__ void embed_kernel(const int* __restrict__ ids, const float* __restrict__ emb,
                             float* __restrict__ src, unsigned short* __restrict__ srcbf) {
    int r  = blockIdx.x;
    int s  = r % SS;
    int id = ids[r];
    int d0 = threadIdx.x * 4;
    const float c = logf(10000.0f) / 512.0f;
    unsigned short pk[4];
    #pragma unroll
    for (int jj = 0; jj < 4; jj++) {
        int d  = d0 + jj;
        int j2 = d & ~1;
        float freq = expf(-(float)j2 * c);
        float ang  = (float)s * freq;
        float pe   = (d & 1) ? cosf(ang) : sinf(ang);
        float x = emb[id * DD + d] + pe;
        src[r * DD + d] = x;
        pk[jj] = f2bf(x);
    }
    *(uint2*)PANEL(srcbf, MM, r, d0) = *(uint2*)pk;
}

// ---------------------------------------------------------------------------
__global__ void kpos_kernel(const float* __restrict__ Wpos, unsigned short* __restrict__ kp) {
    int r = blockIdx.x;
    float p = (float)(SS - 1 - r);
    __shared__ float pe[DD];
    int t = threadIdx.x;
    const float c = logf(10000.0f) / 512.0f;
    {
        int j2 = t & ~1;
        float freq = expf(-(float)j2 * c);
        float ang  = p * freq;
        pe[t] = (t & 1) ? cosf(ang) : sinf(ang);
    }
    __syncthreads();
    float acc = 0.0f;
    for (int k = 0; k < DD; k++) acc += pe[k] * Wpos[k * DD + t];
    kp[r * DD + t] = f2bf(acc);
}

// ---------------------------------------------------------------------------
// Weight -> transposed bf16 panel with row offset into a combined buffer:
// Wt panel rows = Ntot; source W is K x Nsrc; dest rows n_off..n_off+Nsrc-1
__global__ void wtr_off_kernel(const float* __restrict__ W, unsigned short* __restrict__ Wt,
                               int K, int Nsrc, int Ntot, int n_off) {
    int idx = blockIdx.x * 256 + threadIdx.x;
    if (idx >= K * Nsrc) return;
    int k = idx / Nsrc, n = idx - k * Nsrc;
    *PANEL(Wt, Ntot, n_off + n, k) = f2bf(W[idx]);
}

// ---------------------------------------------------------------------------
// bf16 MFMA GEMM, software-pipelined (dbuf, 1 barrier/iter) + LDS-repack
// epilogue. A panel [K/8][M][8]; Bt panel [K/8][N][8]. BM=128.
// CMODE: 0 = fp32 flat (stride N)
//        1 = bf16 panel (rows=M) -> Cb
//        3 = fused gate: xg=sigmoid(x); out=Cf*(1-xg)+Px*xg -> Cf fp32 + Cb panel
//        4 = qkv split: col<512 -> Cf fp32 (stride 512); else Cb flat (stride 1024)
//        5 = p1g1 split: col<2048 -> Cb panel; else Cb2 panel (col-2048)
template<int BN>
__device__ __forceinline__ void stage_tile(const unsigned short* A, const unsigned short* Bt,
        unsigned short* smem, int it, int buf, int m0, int n0, int M, int N,
        int wave, int lane) {
    const unsigned short* gA = A + ((size_t)(it * 4 + wave) * M + m0) * 8;
    unsigned short* lA = smem + buf * 4096 + wave * 1024;
    gl2lds16(gA + lane * 8,        lA + lane * 8);
    gl2lds16(gA + (64 + lane) * 8, lA + (64 + lane) * 8);
    const unsigned short* gB = Bt + ((size_t)(it * 4 + wave) * N + n0) * 8;
    unsigned short* lB = smem + 8192 + buf * (BN * 32) + wave * (BN * 8);
    gl2lds16(gB + lane * 8, lB + lane * 8);
    if (BN == 128) gl2lds16(gB + (64 + lane) * 8, lB + (64 + lane) * 8);
}

template<int ACT, int CMODE, int BN>
__global__ __launch_bounds__(256) void mgemm(const unsigned short* __restrict__ A,
                                             const unsigned short* __restrict__ Bt,
                                             const float* __restrict__ bias,
                                             float* __restrict__ Cf,
                                             unsigned short* __restrict__ Cb,
                                             unsigned short* __restrict__ Cb2,
                                             int M, int N, int K,
                                             const float* __restrict__ Px) {
    const int NF  = BN / 32;
    const int STG = 8192 + 2 * BN * 32;       // dbuf staging (shorts)
    const int SCR = 128 * (BN + 8);           // epilogue scratch (shorts)
    __shared__ __align__(16) unsigned short smem[(STG > SCR) ? STG : SCR];

    int nm = M >> 7, nn = N / BN;
    int bid = blockIdx.x;
    int xcd = bid & 7, slot = bid >> 3;
    int c0 = (xcd * nm) >> 3, c1 = ((xcd + 1) * nm) >> 3;
    int cm = c1 - c0;
    if (slot >= cm * nn) return;
    int m0 = (c0 + (slot % cm)) * 128;
    int n0 = (slot / cm) * BN;

    int t = threadIdx.x, lane = t & 63, wave = t >> 6;
    int quad = lane >> 4, l16 = lane & 15;
    int wm = (wave & 1) * 64, wn = (wave >> 1) * (BN / 2);

    floatx4 acc[4][4];
    #pragma unroll
    for (int i = 0; i < 4; i++)
        #pragma unroll
        for (int j = 0; j < NF; j++) acc[i][j] = (floatx4){0.f, 0.f, 0.f, 0.f};

    int nit = K >> 5;
    stage_tile<BN>(A, Bt, smem, 0, 0, m0, n0, M, N, wave, lane);
    for (int it = 0; it < nit; it++) {
        __syncthreads();   // tile `it` ready (vmcnt drain) + prev reads done
        if (it + 1 < nit)
            stage_tile<BN>(A, Bt, smem, it + 1, (it + 1) & 1, m0, n0, M, N, wave, lane);
        const unsigned short* As = smem + (it & 1) * 4096;
        const unsigned short* Bs = smem + 8192 + (it & 1) * (BN * 32);
        bf16x8 af[4], bfv[4];
        #pragma unroll
        for (int mf = 0; mf < 4; mf++)
            af[mf] = *(const bf16x8*)(As + (quad * 128 + wm + mf * 16 + l16) * 8);
        #pragma unroll
        for (int nf = 0; nf < NF; nf++)
            bfv[nf] = *(const bf16x8*)(Bs + (quad * BN + wn + nf * 16 + l16) * 8);
        #pragma unroll
        for (int mf = 0; mf < 4; mf++)
            #pragma unroll
            for (int nf = 0; nf < NF; nf++)
                acc[mf][nf] = __builtin_amdgcn_mfma_f32_16x16x32_bf16(
                                  af[mf], bfv[nf], acc[mf][nf], 0, 0, 0);
    }
    __syncthreads();   // all frag reads done; smem reusable as scratch

    const int ST = BN + 8;
    if (CMODE == 0 || (CMODE == 4 && n0 < 512)) {
        int ldc = (CMODE == 4) ? 512 : N;
        #pragma unroll
        for (int nf = 0; nf < NF; nf++) {
            int col = n0 + wn + nf * 16 + l16;
            float bv = bias ? bias[col] : 0.0f;
            #pragma unroll
            for (int mf = 0; mf < 4; mf++)
                #pragma unroll
                for (int r = 0; r < 4; r++) {
                    int row = m0 + wm + mf * 16 + quad * 4 + r;
                    float x = acc[mf][nf][r] + bv;
                    if (ACT == 1) x = fmaxf(x, 0.f);
                    else if (ACT == 2) x = tanhf(x);
                    Cf[(size_t)row * ldc + col] = x;
                }
        }
    } else if (CMODE == 3) {
        // fused sigmoid gate + combine; out -> Cf fp32 and scratch bf16
        #pragma unroll
        for (int nf = 0; nf < NF; nf++) {
            int col = n0 + wn + nf * 16 + l16;
            float bv = bias ? bias[col] : 0.0f;
            #pragma unroll
            for (int mf = 0; mf < 4; mf++)
                #pragma unroll
                for (int r = 0; r < 4; r++) {
                    int rrow = wm + mf * 16 + quad * 4 + r;
                    float x = acc[mf][nf][r] + bv;
                    float xg = 1.0f / (1.0f + expf(-x));
                    size_t o = (size_t)(m0 + rrow) * N + col;
                    float out = Cf[o] * (1.0f - xg) + Px[o] * xg;
                    Cf[o] = out;
                    smem[rrow * ST + wn + nf * 16 + l16] = f2bf(out);
                }
        }
        __syncthreads();
        int row = t & 127, hb = t >> 7;
        for (int i = hb; i < BN / 8; i += 2) {
            uint4 vd = *(const uint4*)(smem + row * ST + i * 8);
            int gcol = n0 + i * 8;
            *(uint4*)(Cb + ((size_t)(gcol >> 3) * M + m0 + row) * 8) = vd;
        }
    } else {
        // CMODE 1 / 5 / 4-kv: bf16 via scratch repack
        #pragma unroll
        for (int nf = 0; nf < NF; nf++) {
            int col = n0 + wn + nf * 16 + l16;
            float bv = bias ? bias[col] : 0.0f;
            #pragma unroll
            for (int mf = 0; mf < 4; mf++)
                #pragma unroll
                for (int r = 0; r < 4; r++) {
                    int rrow = wm + mf * 16 + quad * 4 + r;
                    float x = acc[mf][nf][r] + bv;
                    if (ACT == 1) x = fmaxf(x, 0.f);
                    else if (ACT == 2) x = tanhf(x);
                    smem[rrow * ST + wn + nf * 16 + l16] = f2bf(x);
                }
        }
        __syncthreads();
        if (CMODE == 4) {
            // kv flat, stride 1024, col offset n0-512; col-fast lanes (coalesced)
            int rr0 = t >> 4, chk = t & 15;   // BN==128 here
            for (int rr = rr0; rr < 128; rr += 16) {
                uint4 vd = *(const uint4*)(smem + rr * ST + chk * 8);
                *(uint4*)(Cb + (size_t)(m0 + rr) * 1024 + (n0 - 512) + chk * 8) = vd;
            }
        } else {
            int row = t & 127, hb = t >> 7;
            for (int i = hb; i < BN / 8; i += 2) {
                uint4 vd = *(const uint4*)(smem + row * ST + i * 8);
                int gcol = n0 + i * 8;
                unsigned short* dst;
                if (CMODE == 5 && gcol >= 2048)
                    dst = Cb2 + ((size_t)((gcol - 2048) >> 3) * M + m0 + row) * 8;
                else
                    dst = Cb + ((size_t)(gcol >> 3) * M + m0 + row) * 8;
                *(uint4*)dst = vd;
            }
        }
    }
}
static inline int mgemm_grid(int M, int N, int BN) {
    int nm = M >> 7, nn = N / BN;
    int cmmax = 0;
    for (int x = 0; x < 8; x++) {
        int c = ((x + 1) * nm) / 8 - (x * nm) / 8;
        if (c > cmmax) cmmax = c;
    }
    return 8 * cmmax * nn;
}

// ---------------------------------------------------------------------------
// MFMA fused attention v3 (unchanged from round 6)
#define LKP 0
#define LK  12800
#define LV  19456
#define LPS 27648
#define PSW 116
__global__ __launch_bounds__(512, 4) void attn_kernel3(
        const float* __restrict__ q, const unsigned short* __restrict__ kvb,
        const unsigned short* __restrict__ kpbf, const float* __restrict__ u,
        const float* __restrict__ v, const int* __restrict__ len_,
        unsigned short* __restrict__ outp) {
    __shared__ __align__(16) unsigned short lds[40640];
    int b = blockIdx.x >> 3, h = blockIdx.x & 7;
    int t = threadIdx.x, wave = t >> 6, lane = t & 63;
    int quad = lane >> 4, l16 = lane & 15;

    {
        int r8 = lane >> 3;
        int cc = (lane & 7) ^ r8;
        for (int i = wave; i < 25; i += 8) {
            int row = i * 8 + r8;
            gl2lds16(kpbf + (size_t)row * DD + h * 64 + cc * 8,
                     lds + LKP + i * 512 + lane * 8);
        }
        for (int i = wave; i < 13; i += 8) {
            int row = i * 8 + r8;
            gl2lds16(kvb + (size_t)(b * SS + row) * 1024 + h * 128 + cc * 8,
                     lds + LK + i * 512 + lane * 8);
        }
    }
    for (int idx = t; idx < 8192; idx += 512) {
        int j = idx >> 6, d = idx & 63;
        unsigned short vv = kvb[(size_t)(b * SS + j) * 1024 + h * 128 + 64 + d];
        lds[LV + d * 128 + (((j >> 3) ^ (d & 15)) << 3) + (j & 7)] = vv;
    }
    int len = len_[b];
    float ua[2][8], va[2][8];
    #pragma unroll
    for (int kf = 0; kf < 2; kf++)
        #pragma unroll
        for (int i = 0; i < 8; i++) {
            ua[kf][i] = u[h * 64 + kf * 32 + quad * 8 + i];
            va[kf][i] = v[h * 64 + kf * 32 + quad * 8 + i];
        }
    __syncthreads();
    if (wave >= 7) return;

    int s = wave;
    unsigned short* psc = lds + LPS + wave * (16 * PSW);

    int iq = s * 16 + l16; if (iq > 99) iq = 99;
    const float* qrow = q + ((size_t)(b * SS + iq)) * DD + h * 64;
    bf16x8 qu_h[2], qu_l[2], qv_h[2], qv_l[2];
    #pragma unroll
    for (int kf = 0; kf < 2; kf++) {
        float4 q0 = *(const float4*)(qrow + kf * 32 + quad * 8);
        float4 q1 = *(const float4*)(qrow + kf * 32 + quad * 8 + 4);
        float qa[8] = {q0.x, q0.y, q0.z, q0.w, q1.x, q1.y, q1.z, q1.w};
        float xu[8], xv[8];
        #pragma unroll
        for (int i = 0; i < 8; i++) { xu[i] = qa[i] + ua[kf][i]; xv[i] = qa[i] + va[kf][i]; }
        split8(xu, qu_h[kf], qu_l[kf]);
        split8(xv, qv_h[kf], qv_l[kf]);
    }
    floatx4 cacc[7];
    #pragma unroll
    for (int nt = 0; nt < 7; nt++) cacc[nt] = (floatx4){0.f, 0.f, 0.f, 0.f};
    #pragma unroll
    for (int nt = 0; nt < 7; nt++) {
        int rr = nt * 16 + l16;
        #pragma unroll
        for (int kf = 0; kf < 2; kf++) {
            int ch = kf * 4 + quad;
            bf16x8 kb = *(const bf16x8*)(lds + LK + rr * 64 + ((ch ^ (rr & 7)) << 3));
            cacc[nt] = __builtin_amdgcn_mfma_f32_16x16x32_bf16(qu_h[kf], kb, cacc[nt], 0, 0, 0);
            cacc[nt] = __builtin_amdgcn_mfma_f32_16x16x32_bf16(qu_l[kf], kb, cacc[nt], 0, 0, 0);
        }
    }
    int w0 = 84 - 16 * s; if (w0 < 0) w0 = 0;
    {
        floatx4 pacc[8];
        #pragma unroll
        for (int nt = 0; nt < 8; nt++) pacc[nt] = (floatx4){0.f, 0.f, 0.f, 0.f};
        #pragma unroll
        for (int nt = 0; nt < 8; nt++) {
            int rr = w0 + nt * 16 + l16;
            #pragma unroll
            for (int kf = 0; kf < 2; kf++) {
                int ch = kf * 4 + quad;
                bf16x8 pb = *(const bf16x8*)(lds + LKP + rr * 64 + ((ch ^ (rr & 7)) << 3));
                pacc[nt] = __builtin_amdgcn_mfma_f32_16x16x32_bf16(qv_h[kf], pb, pacc[nt], 0, 0, 0);
                pacc[nt] = __builtin_amdgcn_mfma_f32_16x16x32_bf16(qv_l[kf], pb, pacc[nt], 0, 0, 0);
            }
        }
        #pragma unroll
        for (int nt = 0; nt < 7; nt++)
            #pragma unroll
            for (int r = 0; r < 4; r++)
                psc[(quad * 4 + r) * PSW + nt * 16 + l16] = f2bf(pacc[nt][r]);
        if (l16 < 4)
            #pragma unroll
            for (int r = 0; r < 4; r++)
                psc[(quad * 4 + r) * PSW + 112 + l16] = f2bf(pacc[7][r]);
    }
    float sc[7][4];
    #pragma unroll
    for (int nt = 0; nt < 7; nt++)
        #pragma unroll
        for (int r = 0; r < 4; r++) {
            int irow = s * 16 + quad * 4 + r;
            int j = nt * 16 + l16;
            int ro = 99 - irow + j - w0;
            ro = ro < 0 ? 0 : (ro > PSW - 1 ? PSW - 1 : ro);
            float val = (cacc[nt][r] + bf2f(psc[(quad * 4 + r) * PSW + ro])) * SCALE_;
            sc[nt][r] = (j < len) ? val : -1e9f;
        }
    float inv[4];
    #pragma unroll
    for (int r = 0; r < 4; r++) {
        float m_ = sc[0][r];
        #pragma unroll
        for (int nt = 1; nt < 7; nt++) m_ = fmaxf(m_, sc[nt][r]);
        #pragma unroll
        for (int o = 8; o; o >>= 1) m_ = fmaxf(m_, __shfl_xor(m_, o));
        float s_ = 0.f;
        #pragma unroll
        for (int nt = 0; nt < 7; nt++) { sc[nt][r] = expf(sc[nt][r] - m_); s_ += sc[nt][r]; }
        #pragma unroll
        for (int o = 8; o; o >>= 1) s_ += __shfl_xor(s_, o);
        inv[r] = 1.0f / s_;
    }
    bf16x8 zero8 = (bf16x8){0, 0, 0, 0, 0, 0, 0, 0};
    floatx4 oacc[4];
    #pragma unroll
    for (int ntd = 0; ntd < 4; ntd++) oacc[ntd] = (floatx4){0.f, 0.f, 0.f, 0.f};
    #pragma unroll
    for (int pass = 0; pass < 2; pass++) {
        #pragma unroll
        for (int r = 0; r < 4; r++) {
            int row = quad * 4 + r;
            #pragma unroll
            for (int nt = 0; nt < 7; nt++) {
                float pv = sc[nt][r] * inv[r];
                unsigned short ph = f2bf(pv);
                psc[row * PSW + nt * 16 + l16] =
                    (pass == 0) ? ph : f2bf(pv - bf2f(ph));
            }
        }
        bf16x8 pa[4];
        #pragma unroll
        for (int kf = 0; kf < 3; kf++)
            pa[kf] = ld8_u8align(psc + l16 * PSW + kf * 32 + quad * 8);
        pa[3] = (quad < 2) ? ld8_u8align(psc + l16 * PSW + 96 + quad * 8) : zero8;
        #pragma unroll
        for (int ntd = 0; ntd < 4; ntd++) {
            int d = ntd * 16 + l16;
            #pragma unroll
            for (int kf = 0; kf < 4; kf++) {
                int ch = kf * 4 + quad;
                bf16x8 bv = *(const bf16x8*)(lds + LV + d * 128 + ((ch ^ (d & 15)) << 3));
                oacc[ntd] = __builtin_amdgcn_mfma_f32_16x16x32_bf16(pa[kf], bv, oacc[ntd], 0, 0, 0);
            }
        }
    }
    #pragma unroll
    for (int ntd = 0; ntd < 4; ntd++)
        #pragma unroll
        for (int r = 0; r < 4; r++) {
            int irow = s * 16 + quad * 4 + r;
            if (irow < 100) {
                int col = h * 64 + ntd * 16 + l16;
                int row = b * SS + irow;
                *PANEL(outp, MM, row, col) = f2bf(oacc[ntd][r]);
            }
        }
}

// ---------------------------------------------------------------------------
__global__ void ln_kernel(const float* __restrict__ x, const float* __restrict__ a,
                          const float* __restrict__ g, const float* __restrict__ bb,
                          unsigned short* __restrict__ outp) {
    int r = blockIdx.x;
    int t = threadIdx.x;
    float4 xv = *(const float4*)(x + (size_t)r * DD + t * 4);
    float4 av = *(const float4*)(a + (size_t)r * DD + t * 4);
    float v0 = xv.x + av.x, v1 = xv.y + av.y, v2 = xv.z + av.z, v3 = xv.w + av.w;
    float sum = v0 + v1 + v2 + v3;
    float sq  = v0 * v0 + v1 * v1 + v2 * v2 + v3 * v3;
    #pragma unroll
    for (int o = 32; o > 0; o >>= 1) {
        sum += __shfl_down(sum, o);
        sq  += __shfl_down(sq, o);
    }
    __shared__ float ls[2], lq[2];
    if ((t & 63) == 0) { ls[t >> 6] = sum; lq[t >> 6] = sq; }
    __syncthreads();
    float S_ = ls[0] + ls[1], Q_ = lq[0] + lq[1];
    float m   = S_ / 512.0f;
    float var = Q_ / 512.0f - m * m;
    float rs  = rsqrtf(var + 1e-5f);
    float4 gv = *(const float4*)(g  + t * 4);
    float4 bv = *(const float4*)(bb + t * 4);
    unsigned short pk[4];
    pk[0] = f2bf((v0 - m) * rs * gv.x + bv.x);
    pk[1] = f2bf((v1 - m) * rs * gv.y + bv.y);
    pk[2] = f2bf((v2 - m) * rs * gv.z + bv.z);
    pk[3] = f2bf((v3 - m) * rs * gv.w + bv.w);
    *(uint2*)PANEL(outp, MM, r, t * 4) = *(uint2*)pk;
}

// ---------------------------------------------------------------------------
extern "C" void kernel_launch(void* const* d_in, const int* in_sizes, int n_in,
                              void* d_out, int out_size, void* d_ws, size_t ws_size,
                              hipStream_t stream) {
    const int*   ids     = (const int*)  d_in[0];
    const int*   src_len = (const int*)  d_in[1];
    const float* emb     = (const float*)d_in[2];
    const float* Wq      = (const float*)d_in[3];
    const float* Wkv     = (const float*)d_in[4];
    const float* Wpos    = (const float*)d_in[5];
    const float* Wout    = (const float*)d_in[6];
    const float* u       = (const float*)d_in[7];
    const float* v       = (const float*)d_in[8];
    const float* ng      = (const float*)d_in[9];
    const float* nb      = (const float*)d_in[10];
    const float* p1_w    = (const float*)d_in[11];
    const float* p1_b    = (const float*)d_in[12];
    const float* p2_w    = (const float*)d_in[13];
    const float* p2_b    = (const float*)d_in[14];
    const float* g1_w    = (const float*)d_in[15];
    const float* g1_b    = (const float*)d_in[16];
    const float* g2_w    = (const float*)d_in[17];
    const float* g2_b    = (const float*)d_in[18];

    float* src = (float*)d_out;

    float* ws     = (float*)d_ws;
    float* q      = ws;                              // M*512 f
    float* t1     = q    + (size_t)MM * DD;          // M*512 f
    float* proj   = t1   + (size_t)MM * DD;          // M*512 f
    float* p1g1_b = proj + (size_t)MM * DD;          // 2560 f
    unsigned short* kpbf  = (unsigned short*)(p1g1_b + 4096);
    unsigned short* srcbf = kpbf  + (size_t)RR * DD;     // M*512 panel
    unsigned short* netbf = srcbf + (size_t)MM * DD;     // M*512 panel
    unsigned short* t0p   = netbf + (size_t)MM * DD;     // M*512 panel
    unsigned short* kvb   = t0p   + (size_t)MM * DD;     // M*1024 flat
    unsigned short* ffb   = kvb   + (size_t)MM * 2 * DD; // M*2048 panel
    unsigned short* hgb   = ffb   + (size_t)MM * DFFF;   // M*512 panel
    unsigned short* qkv_t  = hgb   + (size_t)MM * DD;    // 1536*512
    unsigned short* wout_t = qkv_t  + 1536 * 512;
    unsigned short* p1g1_t = wout_t + 512 * 512;         // 2560*512
    unsigned short* p2_t   = p1g1_t + 2560 * 512;
    unsigned short* g2_t   = p2_t   + 512 * 2048;

    // one-time prep
    embed_kernel<<<MM, 128, 0, stream>>>(ids, emb, src, srcbf);
    kpos_kernel<<<RR, DD, 0, stream>>>(Wpos, kpbf);
    wtr_off_kernel<<<(512*512 +255)/256, 256, 0, stream>>>(Wq,   qkv_t,  512, 512,  1536, 0);
    wtr_off_kernel<<<(512*1024+255)/256, 256, 0, stream>>>(Wkv,  qkv_t,  512, 1024, 1536, 512);
    wtr_off_kernel<<<(512*512 +255)/256, 256, 0, stream>>>(Wout, wout_t, 512, 512,  512,  0);
    wtr_off_kernel<<<(512*2048+255)/256, 256, 0, stream>>>(p1_w, p1g1_t, 512, 2048, 2560, 0);
    wtr_off_kernel<<<(512*512 +255)/256, 256, 0, stream>>>(g1_w, p1g1_t, 512, 512,  2560, 2048);
    wtr_off_kernel<<<(2048*512+255)/256, 256, 0, stream>>>(p2_w, p2_t,   2048, 512, 512,  0);
    wtr_off_kernel<<<(512*512 +255)/256, 256, 0, stream>>>(g2_w, g2_t,   512, 512,  512,  0);
    hipMemcpyAsync(p1g1_b,        p1_b, 2048 * sizeof(float), hipMemcpyDeviceToDevice, stream);
    hipMemcpyAsync(p1g1_b + 2048, g1_b,  512 * sizeof(float), hipMemcpyDeviceToDevice, stream);

    int gqkv = mgemm_grid(MM, 1536, 128);
    int g64  = mgemm_grid(MM, 512, 64);
    int gp1  = mgemm_grid(MM, 2560, 128);

    for (int layer = 0; layer < NLAYERS; layer++) {
        // q (fp32) + kv (bf16 flat) fused
        mgemm<0,4,128><<<gqkv, 256, 0, stream>>>(
            srcbf, qkv_t, (const float*)nullptr, q, kvb, (unsigned short*)nullptr,
            MM, 1536, 512, (const float*)nullptr);
        attn_kernel3<<<BB * HH, 512, 0, stream>>>(q, kvb, kpbf, u, v, src_len, t0p);
        mgemm<0,0,64><<<g64, 256, 0, stream>>>(
            t0p, wout_t, (const float*)nullptr, t1, (unsigned short*)nullptr,
            (unsigned short*)nullptr, MM, 512, 512, (const float*)nullptr);
        ln_kernel<<<MM, 128, 0, stream>>>(src, t1, ng, nb, netbf);
        // h1 = relu(net@p1+b) -> ffb panel ; hg = relu(net@g1+b) -> hgb panel (fused)
        mgemm<1,5,128><<<gp1, 256, 0, stream>>>(
            netbf, p1g1_t, p1g1_b, (float*)nullptr, ffb, hgb,
            MM, 2560, 512, (const float*)nullptr);
        mgemm<2,0,64><<<g64, 256, 0, stream>>>(
            ffb, p2_t, p2_b, proj, (unsigned short*)nullptr, (unsigned short*)nullptr,
            MM, 512, 2048, (const float*)nullptr);
        // bg=sigmoid(hg@g2+b); src = src*(1-bg)+proj*bg; srcbf panel updated
        mgemm<0,3,64><<<g64, 256, 0, stream>>>(
            hgb, g2_t, g2_b, src, srcbf, (unsigned short*)nullptr,
            MM, 512, 512, proj);
    }
}